// Round 4
// baseline (724.695 us; speedup 1.0000x reference)
//
#include <hip/hip_runtime.h>
#include <hip/hip_bf16.h>
#include <math.h>

#define HW     192
#define PLANE  (HW*HW)        // 36864
#define CIN    64
#define COUT   64
#define NB     4
#define NPIX   (NB*PLANE)     // 147456
#define H2     194
#define W2     195
#define PPLANE (H2*W2)        // 37830 u32 per padded dup plane

typedef __attribute__((ext_vector_type(8))) short bf16x8;
typedef __attribute__((ext_vector_type(4))) float f32x4;

static __device__ __forceinline__ ushort f2bf(float f) {
    __hip_bfloat16 h = __float2bfloat16(f);
    return __builtin_bit_cast(ushort, h);
}
static __device__ __forceinline__ float bflo(unsigned u) {   // low bf16 -> f32
    return __builtin_bit_cast(float, u << 16);
}
static __device__ __forceinline__ float bfhi(unsigned u) {   // high bf16 -> f32
    return __builtin_bit_cast(float, u & 0xffff0000u);
}

// ---------------- Kernel 1: pad+dup x to bf16 pairs, + weight prep ----------
// xpd[bc][y][col] = (bf16 x[y-1][col-1], bf16 x[y-1][col]) ; zero outside
__global__ __launch_bounds__(256) void kpadprep(
    const float* __restrict__ x,
    const float* __restrict__ wc, const float* __restrict__ w_p,
    const float* __restrict__ w_m,
    unsigned* __restrict__ xpd, ushort* __restrict__ wbf, ushort* __restrict__ womf)
{
    int blk = blockIdx.x;
    if (blk < (256 * H2 * W2) / 256) {          // 37830 blocks: pad path
        int i   = blk * 256 + threadIdx.x;      // 0..9,684,479 exact
        int col = i % W2;
        int t2  = i / W2;
        int y   = t2 % H2;
        int bc  = t2 / H2;                      // 0..255
        float lo = 0.f, hi = 0.f;
        if (y >= 1 && y <= HW) {
            const float* row = x + (size_t)bc * PLANE + (y - 1) * HW;
            if (col >= 1 && col <= HW) lo = row[col - 1];
            if (col <= HW - 1)         hi = row[col];
        }
        xpd[i] = (unsigned)f2bf(lo) | ((unsigned)f2bf(hi) << 16);
        return;
    }
    int i = (blk - 37830) * 256 + threadIdx.x;  // 27 blocks -> 0..6911
    if (i < 4608) {
        int lane  = i & 63;
        int rc    = i >> 6;
        int chunk = rc % 18;
        int og    = rc / 18;
        int o  = og * 16 + (lane & 15);
        int k0 = chunk * 32 + (lane >> 4) * 8;
        ushort v[8];
#pragma unroll
        for (int j = 0; j < 8; ++j) v[j] = f2bf(wc[o * 576 + k0 + j]);
        ((uint4*)wbf)[i] = *(uint4*)v;
    } else if (i < 4608 + 2304) {
        int ii    = i - 4608;
        int lane  = ii & 63;
        int rc    = ii >> 6;                    // 0..35
        int chunk = rc % 18;
        int og    = rc / 18;                    // 0..1
        int co = og * 16 + (lane & 15);
        int k0 = chunk * 32 + (lane >> 4) * 8;
        ushort v[8];
#pragma unroll
        for (int j = 0; j < 8; ++j) {
            float w = 0.f;
            if (co < 18)      w = w_p[co * 576 + k0 + j];
            else if (co < 27) w = w_m[(co - 18) * 576 + k0 + j];
            v[j] = f2bf(w);
        }
        ((uint4*)womf)[ii] = *(uint4*)v;
    }
}

// ---------------- Kernel 2: offsets (MFMA) + sampling + main GEMM (MFMA) ----
// block = 256 threads (4 waves) handles 16 consecutive pixels (same batch/row)
__global__ __launch_bounds__(256, 5) void kdeform(
    const unsigned* __restrict__ xpd,
    const ushort* __restrict__ wbf,
    const ushort* __restrict__ womf,
    const float* __restrict__ b_p, const float* __restrict__ b_m,
    ushort* __restrict__ outp,          // (B, 64, H, W) bf16
    float* __restrict__ sums)           // [2][4][64] partial sums / sumsq
{
    __shared__ ushort sXF[9216];        // 18432 B fragment-order tile
    __shared__ float4 sG[9][16];        // 2304 B bilinear*mask weights (lo0,hi0,lo1,hi1)
    __shared__ int2   sO[9][16];        // 1152 B row0/row1 u32-element offsets
    __shared__ float  sOM[32][17];      // 2176 B offset-conv result (padded)

    int t    = threadIdx.x;
    int pix0 = blockIdx.x * 16;
    int b    = pix0 / PLANE;
    int rem  = pix0 - b * PLANE;
    int h    = rem / HW;
    int w0   = rem - h * HW;            // multiple of 16
    int p    = t & 15;
    int q16  = t >> 4;

    const unsigned* xpb = xpd + (size_t)b * CIN * PPLANE;

    // ---- phase A: stage im2col tile (bf16) in fragment order ----
#pragma unroll
    for (int it = 0; it < 9; ++it) {
        int k0 = 4 * q16 + 64 * it;
        ushort pk[4];
#pragma unroll
        for (int jj = 0; jj < 4; ++jj) {
            int k = k0 + jj;
            int c = (k * 7282) >> 16;           // k/9
            int n = k - c * 9;
            int dy = n / 3, dx = n - dy * 3;
            pk[jj] = (ushort)(xpb[c * PPLANE + (h + dy) * W2 + (w0 + p + dx)] & 0xffffu);
        }
        int chunk = k0 >> 5, kk0 = k0 & 31;
        int e = (chunk * 64 + (kk0 >> 3) * 16 + p) * 8 + (kk0 & 7);
        *(uint2*)&sXF[e] = *(const uint2*)pk;
    }
    __syncthreads();

    // ---- phase B: offset+mask conv via MFMA (waves 0,1 -> 32 rows) ----
    if (t < 128) {
        int lane = t & 63;
        int og   = t >> 6;
        f32x4 acc = {0.f, 0.f, 0.f, 0.f};
#pragma unroll
        for (int chunk = 0; chunk < 18; ++chunk) {
            bf16x8 a  = *(const bf16x8*)&womf[((og * 18 + chunk) * 64 + lane) * 8];
            bf16x8 bb = *(const bf16x8*)&sXF[(chunk * 64 + lane) * 8];
            acc = __builtin_amdgcn_mfma_f32_16x16x32_bf16(a, bb, acc, 0, 0, 0);
        }
        int col = lane & 15, row0 = (lane >> 4) * 4;
#pragma unroll
        for (int r = 0; r < 4; ++r) sOM[og * 16 + row0 + r][col] = acc[r];
    }
    __syncthreads();

    // ---- phase C: per-(pixel,tap) gather offsets + folded bilinear weights --
    if (t < 144) {
        int pp = t & 15, n = t >> 4;            // n in 0..8
        float offy = sOM[n][pp]      + b_p[n];
        float offx = sOM[9 + n][pp]  + b_p[9 + n];
        float mr   = sOM[18 + n][pp] + b_m[n];
        float m = 1.f / (1.f + __expf(-mr));
        int dy = n / 3, dx = n - dy * 3;
        float py = (float)(h + dy) + offy;      // padded coords
        float px = (float)(w0 + pp + dx) + offx;
        float fy = floorf(py), fx = floorf(px);
        float qy0 = fminf(fmaxf(fy,       0.f), 193.f);
        float qy1 = fminf(fmaxf(fy + 1.f, 0.f), 193.f);
        float qx0 = fminf(fmaxf(fx,       0.f), 193.f);
        float qx1 = fminf(fmaxf(fx + 1.f, 0.f), 193.f);
        float pyc = fminf(fmaxf(py, 0.f), 193.f);
        float pxc = fminf(fmaxf(px, 0.f), 193.f);
        float ay = 1.f + qy0 - pyc, by = 1.f - (qy1 - pyc);
        float ax = 1.f + qx0 - pxc, bx = 1.f - (qx1 - pxc);
        int ix0 = (int)qx0, ix1 = (int)qx1;
        // fold x-clamp: when ix1==ix0 both x-corners read the same texel;
        // reference then applies (ax+bx) to it. One u32 covers (ix0, ix0+1).
        float whi = (ix1 > ix0) ? bx : 0.f;
        float wlo = ax + bx - whi;
        int A0 = (int)qy0 * W2 + ix0;           // u32 element offsets
        int A1 = (int)qy1 * W2 + ix0;
        sO[n][pp] = make_int2(A0, A1);
        sG[n][pp] = make_float4(ay * wlo * m, ay * whi * m, by * wlo * m, by * whi * m);
    }
    __syncthreads();

    // ---- phase D: bilinear sampling -> overwrite sXF with x_s (bf16) ----
    {
        int2 Oreg[9];
#pragma unroll
        for (int n = 0; n < 9; ++n) Oreg[n] = sO[n][p];
        const unsigned* pb = xpb + (size_t)(4 * q16) * PPLANE;
#pragma unroll
        for (int ci = 0; ci < 4; ++ci) {
            const unsigned* pc = pb + ci * PPLANE;
            unsigned r0[9], r1[9];
#pragma unroll
            for (int n = 0; n < 9; ++n) { r0[n] = pc[Oreg[n].x]; r1[n] = pc[Oreg[n].y]; }
#pragma unroll
            for (int n = 0; n < 9; ++n) {
                float4 G = sG[n][p];
                float v = G.x * bflo(r0[n]) + G.y * bfhi(r0[n])
                        + G.z * bflo(r1[n]) + G.w * bfhi(r1[n]);
                int k = (4 * q16 + ci) * 9 + n;
                sXF[(k >> 5) * 512 + ((k & 31) >> 3) * 128 + p * 8 + (k & 7)] = f2bf(v);
            }
        }
    }
    __syncthreads();

    // ---- phase E: main MFMA GEMM, stats reduce, store bf16 ----
    {
        int lane = t & 63;
        int og   = t >> 6;
        f32x4 acc = {0.f, 0.f, 0.f, 0.f};
#pragma unroll
        for (int chunk = 0; chunk < 18; ++chunk) {
            bf16x8 a  = *(const bf16x8*)&wbf[((og * 18 + chunk) * 64 + lane) * 8];
            bf16x8 bb = *(const bf16x8*)&sXF[(chunk * 64 + lane) * 8];
            acc = __builtin_amdgcn_mfma_f32_16x16x32_bf16(a, bb, acc, 0, 0, 0);
        }
        int col = lane & 15, row0 = (lane >> 4) * 4;

        // per-channel partial stats: reduce over the 16 cols of each 16-lane group
        float s[4], s2[4];
#pragma unroll
        for (int r = 0; r < 4; ++r) { s[r] = acc[r]; s2[r] = acc[r] * acc[r]; }
#pragma unroll
        for (int m = 1; m < 16; m <<= 1) {
#pragma unroll
            for (int r = 0; r < 4; ++r) {
                s[r]  += __shfl_xor(s[r],  m);
                s2[r] += __shfl_xor(s2[r], m);
            }
        }
        if (col == 0) {
            float* sb = sums + (size_t)b * 64;
#pragma unroll
            for (int r = 0; r < 4; ++r) {
                int ch = og * 16 + row0 + r;
                atomicAdd(&sb[ch], s[r]);
                atomicAdd(&sb[256 + ch], s2[r]);
            }
        }

        ushort* ob = outp + ((size_t)(b * COUT + og * 16 + row0)) * PLANE + rem + col;
        ob[0]                 = f2bf(acc[0]);
        ob[(size_t)PLANE]     = f2bf(acc[1]);
        ob[2 * (size_t)PLANE] = f2bf(acc[2]);
        ob[3 * (size_t)PLANE] = f2bf(acc[3]);
    }
}

// ---------------- Kernel 3: BN finalize + ReLU + 2x2 maxpool ----------------
__global__ __launch_bounds__(256) void kbnpool(
    const ushort* __restrict__ outp, const float* __restrict__ sums,
    const float* __restrict__ gamma, const float* __restrict__ beta,
    float* __restrict__ out)
{
    int i = blockIdx.x * 256 + threadIdx.x;   // 0..2359295 exact
    int wo  = i % 96;
    int tmp = i / 96;
    int ho  = tmp % 96; tmp /= 96;
    int o   = tmp % 64;
    int b   = tmp / 64;
    float s  = sums[o]       + sums[64 + o]        + sums[128 + o]       + sums[192 + o];
    float s2 = sums[256 + o] + sums[256 + 64 + o]  + sums[256 + 128 + o] + sums[256 + 192 + o];
    float inv  = 1.f / (float)(NB * PLANE);
    float mean = s * inv;
    float var  = s2 * inv - mean * mean;
    float rsq  = rsqrtf(var + 1e-5f);
    float g  = gamma[o] * rsq;
    float bt = beta[o] - mean * g;
    const ushort* pl = outp + ((size_t)(b * COUT + o)) * PLANE + (2 * ho) * HW + 2 * wo;
    unsigned u01 = *(const unsigned*)pl;
    unsigned u23 = *(const unsigned*)(pl + HW);
    float y00 = fmaxf(g * bflo(u01) + bt, 0.f);
    float y01 = fmaxf(g * bfhi(u01) + bt, 0.f);
    float y10 = fmaxf(g * bflo(u23) + bt, 0.f);
    float y11 = fmaxf(g * bfhi(u23) + bt, 0.f);
    out[i] = fmaxf(fmaxf(y00, y01), fmaxf(y10, y11));
}

// ---------------- launcher --------------------------------------------------
extern "C" void kernel_launch(void* const* d_in, const int* in_sizes, int n_in,
                              void* d_out, int out_size, void* d_ws, size_t ws_size,
                              hipStream_t stream)
{
    const float* x      = (const float*)d_in[0];
    const float* w_p    = (const float*)d_in[1];
    const float* b_p    = (const float*)d_in[2];
    const float* w_m    = (const float*)d_in[3];
    const float* b_m    = (const float*)d_in[4];
    const float* w_conv = (const float*)d_in[5];
    const float* gamma  = (const float*)d_in[6];
    const float* beta   = (const float*)d_in[7];
    float* out = (float*)d_out;

    char* ws = (char*)d_ws;
    unsigned* xpd  = (unsigned*)ws;                  // 256*37830*4 = 38,737,920 B
    ushort*   outp = (ushort*)(ws + 38737920);       // 18,874,368 B
    float*    sums = (float*)(ws + 57612288);        // 512 floats = 2048 B
    ushort*   wbf  = (ushort*)(ws + 57614336);       // 73,728 B
    ushort*   womf = (ushort*)(ws + 57688064);       // 36,864 B  (end ~57.7 MB)

    hipMemsetAsync(sums, 0, 2048, stream);
    kpadprep<<<37830 + 27, 256, 0, stream>>>(x, w_conv, w_p, w_m, xpd, wbf, womf);
    kdeform<<<NPIX / 16, 256, 0, stream>>>(xpd, wbf, womf, b_p, b_m, outp, sums);
    kbnpool<<<(NB * COUT * 96 * 96) / 256, 256, 0, stream>>>(outp, sums, gamma, beta, out);
}

// Round 5
// 292.870 us; speedup vs baseline: 2.4745x; 2.4745x over previous
//
#include <hip/hip_runtime.h>
#include <hip/hip_bf16.h>
#include <math.h>

#define HW     192
#define PLANE  (HW*HW)        // 36864
#define CIN    64
#define COUT   64
#define NB     4
#define NPIX   (NB*PLANE)     // 147456
#define H2     194
#define W2     200
#define PPLANE (H2*W2)        // 38800 u16 per padded plane
#define WROWS  7
#define WCOLS  24             // staged window per channel: 7x24 bf16 = 336 B

typedef __attribute__((ext_vector_type(8))) short bf16x8;
typedef __attribute__((ext_vector_type(4))) float f32x4;

static __device__ __forceinline__ ushort f2bf(float f) {
    __hip_bfloat16 h = __float2bfloat16(f);
    return __builtin_bit_cast(ushort, h);
}
static __device__ __forceinline__ float bf2f(ushort u) {
    return __builtin_bit_cast(float, ((unsigned)u) << 16);
}

// ---------------- Kernel 1: bf16 zero-padded image + weight prep ------------
// xp[bc][y][col]: y 0..193, col 0..199; data at [1..192][1..192] -> padded
// coords 0..193 valid, cols 194..199 zero (overread margin).
__global__ __launch_bounds__(256) void kpadprep(
    const float* __restrict__ x,
    const float* __restrict__ wc, const float* __restrict__ w_p,
    const float* __restrict__ w_m,
    unsigned* __restrict__ xp32, ushort* __restrict__ wbf, ushort* __restrict__ womf)
{
    int blk = blockIdx.x;
    if (blk < 19400) {                          // pad path: u32 = 2 cols
        int i  = blk * 256 + threadIdx.x;       // 0..4,966,399 exact (256*194*100)
        int c2 = (i % 100) * 2;
        int t2 = i / 100;
        int y  = t2 % H2;
        int bc = t2 / H2;
        float lo = 0.f, hi = 0.f;
        if (y >= 1 && y <= HW) {
            const float* row = x + (size_t)bc * PLANE + (y - 1) * HW;
            if (c2 >= 1 && c2 <= HW)     lo = row[c2 - 1];
            if (c2 + 1 >= 1 && c2 + 1 <= HW) hi = row[c2];
        }
        xp32[i] = (unsigned)f2bf(lo) | ((unsigned)f2bf(hi) << 16);
        return;
    }
    int i = (blk - 19400) * 256 + threadIdx.x;  // 27 blocks -> 0..6911
    if (i < 4608) {
        int lane  = i & 63;
        int rc    = i >> 6;
        int chunk = rc % 18;
        int og    = rc / 18;
        int o  = og * 16 + (lane & 15);
        int k0 = chunk * 32 + (lane >> 4) * 8;
        ushort v[8];
#pragma unroll
        for (int j = 0; j < 8; ++j) v[j] = f2bf(wc[o * 576 + k0 + j]);
        ((uint4*)wbf)[i] = *(uint4*)v;
    } else if (i < 4608 + 2304) {
        int ii    = i - 4608;
        int lane  = ii & 63;
        int rc    = ii >> 6;
        int chunk = rc % 18;
        int og    = rc / 18;
        int co = og * 16 + (lane & 15);
        int k0 = chunk * 32 + (lane >> 4) * 8;
        ushort v[8];
#pragma unroll
        for (int j = 0; j < 8; ++j) {
            float w = 0.f;
            if (co < 18)      w = w_p[co * 576 + k0 + j];
            else if (co < 27) w = w_m[(co - 18) * 576 + k0 + j];
            v[j] = f2bf(w);
        }
        ((uint4*)womf)[ii] = *(uint4*)v;
    }
}

// ---------------- Kernel 2: window-staged offsets + sampling + GEMM ---------
// block = 256 threads (4 waves) handles 16 consecutive pixels (same batch/row)
__global__ __launch_bounds__(256, 4) void kdeform(
    const ushort* __restrict__ xp,
    const ushort* __restrict__ wbf,
    const ushort* __restrict__ womf,
    const float* __restrict__ b_p, const float* __restrict__ b_m,
    ushort* __restrict__ outp)          // (B, 64, H, W) bf16
{
    __shared__ ushort sWin[CIN * WROWS * WCOLS];  // 21504 B staged x window
    __shared__ ushort sXF[9216];                  // 18432 B fragment tile
    __shared__ float4 sG[9][16];                  // 2304 B bilinear*mask weights
    __shared__ int    sO[9][16];                  // 576 B packed corner coords
    __shared__ float  sOM[32][17];                // 2176 B offset-conv result
    __shared__ int    sFlag;

    int t    = threadIdx.x;
    int pix0 = blockIdx.x * 16;
    int b    = pix0 / PLANE;
    int rem  = pix0 - b * PLANE;
    int h    = rem / HW;
    int w0   = rem - h * HW;            // multiple of 16
    int p    = t & 15;
    int q16  = t >> 4;

    int rbase  = min(max(h - 2, 0), H2 - WROWS);       // 0..187
    int wbase2 = (min(max(w0 - 2, 0), 194 - 22)) & ~1; // even, 0..172

    const ushort* xpb = xp + (size_t)b * CIN * PPLANE;
    if (t == 0) sFlag = 0;

    // ---- phase S: stage 64ch x 7row x 24col bf16 window into LDS ----
    {
        const unsigned* xpb32 = (const unsigned*)xpb;
        for (int pair = t; pair < CIN * WROWS; pair += 256) {   // 448 pairs
            int ch = pair / WROWS;
            int r  = pair - ch * WROWS;
            const unsigned* src = xpb32 + ((ch * PPLANE + (rbase + r) * W2 + wbase2) >> 1);
            unsigned tmp[12];
#pragma unroll
            for (int j = 0; j < 12; ++j) tmp[j] = src[j];
            uint4* dst = (uint4*)&sWin[ch * (WROWS * WCOLS) + r * WCOLS];
            dst[0] = *(uint4*)&tmp[0];
            dst[1] = *(uint4*)&tmp[4];
            dst[2] = *(uint4*)&tmp[8];
        }
    }
    __syncthreads();

    // ---- phase A: im2col fragments from LDS window ----
    {
        int hr = h - rbase, wr = w0 - wbase2;
#pragma unroll
        for (int it = 0; it < 9; ++it) {
            int k0 = 4 * q16 + 64 * it;
            ushort pk[4];
#pragma unroll
            for (int jj = 0; jj < 4; ++jj) {
                int k = k0 + jj;
                int c = (k * 7282) >> 16;           // k/9
                int n = k - c * 9;
                int dy = n / 3, dx = n - dy * 3;
                pk[jj] = sWin[c * (WROWS * WCOLS) + (hr + dy) * WCOLS + (wr + p + dx)];
            }
            int chunk = k0 >> 5, kk0 = k0 & 31;
            int e = (chunk * 64 + (kk0 >> 3) * 16 + p) * 8 + (kk0 & 7);
            *(uint2*)&sXF[e] = *(const uint2*)pk;
        }
    }
    __syncthreads();

    // ---- phase B: offset+mask conv via MFMA (waves 0,1 -> 32 rows) ----
    if (t < 128) {
        int lane = t & 63;
        int og   = t >> 6;
        f32x4 acc = {0.f, 0.f, 0.f, 0.f};
#pragma unroll
        for (int chunk = 0; chunk < 18; ++chunk) {
            bf16x8 a  = *(const bf16x8*)&womf[((og * 18 + chunk) * 64 + lane) * 8];
            bf16x8 bb = *(const bf16x8*)&sXF[(chunk * 64 + lane) * 8];
            acc = __builtin_amdgcn_mfma_f32_16x16x32_bf16(a, bb, acc, 0, 0, 0);
        }
        int col = lane & 15, row0 = (lane >> 4) * 4;
#pragma unroll
        for (int r = 0; r < 4; ++r) sOM[og * 16 + row0 + r][col] = acc[r];
    }
    __syncthreads();

    // ---- phase C: per-(pixel,tap) corner coords + bilinear*mask weights ----
    if (t < 144) {
        int pp = t & 15, n = t >> 4;
        float offy = sOM[n][pp]      + b_p[n];
        float offx = sOM[9 + n][pp]  + b_p[9 + n];
        float mr   = sOM[18 + n][pp] + b_m[n];
        float m = 1.f / (1.f + __expf(-mr));
        int dy = n / 3, dx = n - dy * 3;
        float py = (float)(h + dy) + offy;      // padded coords
        float px = (float)(w0 + pp + dx) + offx;
        float fy = floorf(py), fx = floorf(px);
        float qy0 = fminf(fmaxf(fy,       0.f), 193.f);
        float qy1 = fminf(fmaxf(fy + 1.f, 0.f), 193.f);
        float qx0 = fminf(fmaxf(fx,       0.f), 193.f);
        float qx1 = fminf(fmaxf(fx + 1.f, 0.f), 193.f);
        float pyc = fminf(fmaxf(py, 0.f), 193.f);
        float pxc = fminf(fmaxf(px, 0.f), 193.f);
        float ay = 1.f + qy0 - pyc, by = 1.f - (qy1 - pyc);
        float ax = 1.f + qx0 - pxc, bx = 1.f - (qx1 - pxc);
        int ry0 = (int)qy0, ry1 = (int)qy1;
        int cx0 = (int)qx0, cx1 = (int)qx1;
        int xs  = cx1 - cx0;                    // 0 or 1 (clamp handled by dup read)
        sO[n][pp] = ry0 | (ry1 << 8) | (cx0 << 16) | (xs << 24);
        sG[n][pp] = make_float4(ay * ax * m, ay * bx * m, by * ax * m, by * bx * m);
        if (ry0 < rbase || ry1 > rbase + (WROWS - 1) ||
            cx0 < wbase2 || cx1 > wbase2 + (WCOLS - 1))
            atomicOr(&sFlag, 1);
    }
    __syncthreads();

    // ---- phase D: bilinear sampling (LDS window) -> x_s fragments ----
    {
        int Opk[9]; float4 Gg[9];
#pragma unroll
        for (int n = 0; n < 9; ++n) { Opk[n] = sO[n][p]; Gg[n] = sG[n][p]; }
        ushort vreg[36] __attribute__((aligned(8)));

        if (sFlag == 0) {
            int i0[9], i1[9], xs_[9];
#pragma unroll
            for (int n = 0; n < 9; ++n) {
                int ry0 = Opk[n] & 255, ry1 = (Opk[n] >> 8) & 255;
                int cx0 = (Opk[n] >> 16) & 255;
                int cr  = cx0 - wbase2;
                i0[n]  = (ry0 - rbase) * WCOLS + cr;
                i1[n]  = (ry1 - rbase) * WCOLS + cr;
                xs_[n] = (Opk[n] >> 24) & 255;
            }
#pragma unroll
            for (int ci = 0; ci < 4; ++ci) {
                const ushort* wcp = &sWin[(4 * q16 + ci) * (WROWS * WCOLS)];
#pragma unroll
                for (int n = 0; n < 9; ++n) {
                    float v00 = bf2f(wcp[i0[n]]);
                    float v01 = bf2f(wcp[i0[n] + xs_[n]]);
                    float v10 = bf2f(wcp[i1[n]]);
                    float v11 = bf2f(wcp[i1[n] + xs_[n]]);
                    float4 G = Gg[n];
                    vreg[ci * 9 + n] =
                        f2bf(G.x * v00 + G.y * v01 + G.z * v10 + G.w * v11);
                }
            }
        } else {
            // rare fallback: out-of-window sample somewhere in this block
#pragma unroll
            for (int ci = 0; ci < 4; ++ci) {
                const ushort* xc = xpb + (size_t)(4 * q16 + ci) * PPLANE;
#pragma unroll
                for (int n = 0; n < 9; ++n) {
                    int ry0 = Opk[n] & 255, ry1 = (Opk[n] >> 8) & 255;
                    int cx0 = (Opk[n] >> 16) & 255, xs = (Opk[n] >> 24) & 255;
                    float v00 = bf2f(xc[ry0 * W2 + cx0]);
                    float v01 = bf2f(xc[ry0 * W2 + cx0 + xs]);
                    float v10 = bf2f(xc[ry1 * W2 + cx0]);
                    float v11 = bf2f(xc[ry1 * W2 + cx0 + xs]);
                    float4 G = Gg[n];
                    vreg[ci * 9 + n] =
                        f2bf(G.x * v00 + G.y * v01 + G.z * v10 + G.w * v11);
                }
            }
        }
#pragma unroll
        for (int g = 0; g < 9; ++g) {
            int k0 = 36 * q16 + 4 * g;
            int e = (k0 >> 5) * 512 + ((k0 & 31) >> 3) * 128 + p * 8 + (k0 & 7);
            *(uint2*)&sXF[e] = *(const uint2*)&vreg[4 * g];
        }
    }
    __syncthreads();

    // ---- phase E: main MFMA GEMM, store bf16 ----
    {
        int lane = t & 63;
        int og   = t >> 6;
        f32x4 acc = {0.f, 0.f, 0.f, 0.f};
#pragma unroll
        for (int chunk = 0; chunk < 18; ++chunk) {
            bf16x8 a  = *(const bf16x8*)&wbf[((og * 18 + chunk) * 64 + lane) * 8];
            bf16x8 bb = *(const bf16x8*)&sXF[(chunk * 64 + lane) * 8];
            acc = __builtin_amdgcn_mfma_f32_16x16x32_bf16(a, bb, acc, 0, 0, 0);
        }
        int col = lane & 15, row0 = (lane >> 4) * 4;
        ushort* ob = outp + ((size_t)(b * COUT + og * 16 + row0)) * PLANE + rem + col;
        ob[0]                 = f2bf(acc[0]);
        ob[(size_t)PLANE]     = f2bf(acc[1]);
        ob[2 * (size_t)PLANE] = f2bf(acc[2]);
        ob[3 * (size_t)PLANE] = f2bf(acc[3]);
    }
}

// ---------------- Kernel 3: per-channel batch stats (bf16 in) ---------------
__global__ __launch_bounds__(256) void kstats(
    const ushort* __restrict__ outp, float* __restrict__ stats)
{
    int o = blockIdx.x;
    int t = threadIdx.x;
    float s = 0.f, s2 = 0.f;
    for (int b = 0; b < NB; ++b) {
        const uint4* pl = (const uint4*)(outp + ((size_t)(b * COUT + o)) * PLANE);
        for (int i = t; i < PLANE / 8; i += 256) {
            uint4 v = pl[i];
            unsigned ua[4] = {v.x, v.y, v.z, v.w};
#pragma unroll
            for (int j = 0; j < 4; ++j) {
                float lo = __builtin_bit_cast(float, ua[j] << 16);
                float hi = __builtin_bit_cast(float, ua[j] & 0xffff0000u);
                s  += lo + hi;
                s2 += lo * lo + hi * hi;
            }
        }
    }
    __shared__ float rs[256], rs2[256];
    rs[t] = s; rs2[t] = s2;
    __syncthreads();
    for (int st = 128; st > 0; st >>= 1) {
        if (t < st) { rs[t] += rs[t + st]; rs2[t] += rs2[t + st]; }
        __syncthreads();
    }
    if (t == 0) {
        float cnt  = (float)(NB * PLANE);
        float mean = rs[0] / cnt;
        float var  = rs2[0] / cnt - mean * mean;
        stats[o]      = mean;
        stats[64 + o] = rsqrtf(var + 1e-5f);
    }
}

// ---------------- Kernel 4: BN + ReLU + 2x2 maxpool (bf16 in, f32 out) ------
__global__ __launch_bounds__(256) void kbnpool(
    const ushort* __restrict__ outp, const float* __restrict__ stats,
    const float* __restrict__ gamma, const float* __restrict__ beta,
    float* __restrict__ out)
{
    int i = blockIdx.x * 256 + threadIdx.x;   // 0..2359295 exact
    int wo  = i % 96;
    int tmp = i / 96;
    int ho  = tmp % 96; tmp /= 96;
    int o   = tmp % 64;
    int b   = tmp / 64;
    float mean = stats[o], rsq = stats[64 + o];
    float g  = gamma[o] * rsq;
    float bt = beta[o] - mean * g;
    const ushort* pl = outp + ((size_t)(b * COUT + o)) * PLANE + (2 * ho) * HW + 2 * wo;
    unsigned u01 = *(const unsigned*)pl;
    unsigned u23 = *(const unsigned*)(pl + HW);
    float y00 = fmaxf(g * __builtin_bit_cast(float, u01 << 16)         + bt, 0.f);
    float y01 = fmaxf(g * __builtin_bit_cast(float, u01 & 0xffff0000u) + bt, 0.f);
    float y10 = fmaxf(g * __builtin_bit_cast(float, u23 << 16)         + bt, 0.f);
    float y11 = fmaxf(g * __builtin_bit_cast(float, u23 & 0xffff0000u) + bt, 0.f);
    out[i] = fmaxf(fmaxf(y00, y01), fmaxf(y10, y11));
}

// ---------------- launcher --------------------------------------------------
extern "C" void kernel_launch(void* const* d_in, const int* in_sizes, int n_in,
                              void* d_out, int out_size, void* d_ws, size_t ws_size,
                              hipStream_t stream)
{
    const float* x      = (const float*)d_in[0];
    const float* w_p    = (const float*)d_in[1];
    const float* b_p    = (const float*)d_in[2];
    const float* w_m    = (const float*)d_in[3];
    const float* b_m    = (const float*)d_in[4];
    const float* w_conv = (const float*)d_in[5];
    const float* gamma  = (const float*)d_in[6];
    const float* beta   = (const float*)d_in[7];
    float* out = (float*)d_out;

    char* ws = (char*)d_ws;
    ushort* xp    = (ushort*)ws;                    // 256*38800*2 = 19,865,600 B
    ushort* outp  = (ushort*)(ws + 19865600);       // 18,874,368 B
    float*  stats = (float*)(ws + 38739968);        // 512 B
    ushort* wbf   = (ushort*)(ws + 38740480);       // 73,728 B
    ushort* womf  = (ushort*)(ws + 38814208);       // 36,864 B

    kpadprep<<<19400 + 27, 256, 0, stream>>>(x, w_conv, w_p, w_m,
                                             (unsigned*)xp, wbf, womf);
    kdeform<<<NPIX / 16, 256, 0, stream>>>(xp, wbf, womf, b_p, b_m, outp);
    kstats<<<64, 256, 0, stream>>>(outp, stats);
    kbnpool<<<(NB * COUT * 96 * 96) / 256, 256, 0, stream>>>(outp, stats, gamma, beta, out);
}

// Round 6
// 192.051 us; speedup vs baseline: 3.7734x; 1.5250x over previous
//
#include <hip/hip_runtime.h>
#include <hip/hip_bf16.h>
#include <math.h>

#define HW     192
#define PLANE  (HW*HW)        // 36864
#define CIN    64
#define COUT   64
#define NB     4
#define NPIX   (NB*PLANE)     // 147456
#define H2     194
#define W2     200
#define WR     7
#define WC     24
#define NPOS   (WR*WC)        // 168

typedef __attribute__((ext_vector_type(8))) short bf16x8;
typedef __attribute__((ext_vector_type(4))) float f32x4;

static __device__ __forceinline__ ushort f2bf(float f) {
    __hip_bfloat16 h = __float2bfloat16(f);
    return __builtin_bit_cast(ushort, h);
}
static __device__ __forceinline__ float bf2f(ushort u) {
    return __builtin_bit_cast(float, ((unsigned)u) << 16);
}

// ---------------- Kernel 1: transpose x -> channel-last padded bf16 + weights
// xt[b][y][col][c]: y 0..193, col 0..199, c 0..63; data at y,col in [1..192]
__global__ __launch_bounds__(256) void kpadprep(
    const float* __restrict__ x,
    const float* __restrict__ wc, const float* __restrict__ w_p,
    const float* __restrict__ w_m,
    ushort* __restrict__ xt, ushort* __restrict__ wbf, ushort* __restrict__ womf)
{
    int blk = blockIdx.x;
    int t   = threadIdx.x;
    if (blk < NB * H2) {                     // transpose path: one (b, y) row
        __shared__ ushort sT[W2 * 72];       // [col][c], col-stride 72 (144B, 16B-mult)
        int b = blk / H2, y = blk % H2;
        const float* xb = x + (size_t)b * CIN * PLANE;
        bool yok = (y >= 1 && y <= HW);
#pragma unroll
        for (int it = 0; it < 25; ++it) {
            int idx = t + 256 * it;          // 0..6399 = 32 c-pairs x 200 cols
            int cp  = (idx * 5243) >> 20;    // idx/200
            int col = idx - cp * 200;
            int c   = cp * 2;
            float v0 = 0.f, v1 = 0.f;
            if (yok && col >= 1 && col <= HW) {
                const float* s0 = xb + (size_t)c * PLANE + (y - 1) * HW + (col - 1);
                v0 = s0[0]; v1 = s0[PLANE];
            }
            *(unsigned*)&sT[col * 72 + c] =
                (unsigned)f2bf(v0) | ((unsigned)f2bf(v1) << 16);
        }
        __syncthreads();
        uint4* dst = (uint4*)(xt + ((size_t)(b * H2 + y) * W2) * 64);
#pragma unroll
        for (int it = 0; it < 7; ++it) {
            int idx = t + 256 * it;          // 0..1599 = 200 cols x 8 octets
            if (idx < 1600) {
                int col = idx >> 3, g = idx & 7;
                dst[idx] = *(uint4*)&sT[col * 72 + g * 8];
            }
        }
        return;
    }
    // weight prep path (27 blocks). k-order: k = n*64 + c
    int i = (blk - NB * H2) * 256 + t;       // 0..6911
    if (i < 4608) {
        int lane  = i & 63;
        int rc    = i >> 6;
        int chunk = rc % 18;
        int og    = rc / 18;
        int o  = og * 16 + (lane & 15);
        int k0 = chunk * 32 + (lane >> 4) * 8;
        ushort v[8];
#pragma unroll
        for (int j = 0; j < 8; ++j) {
            int k = k0 + j, c = k & 63, n = k >> 6;
            v[j] = f2bf(wc[o * 576 + c * 9 + n]);
        }
        ((uint4*)wbf)[i] = *(uint4*)v;
    } else if (i < 6912) {
        int ii    = i - 4608;
        int lane  = ii & 63;
        int rc    = ii >> 6;
        int chunk = rc % 18;
        int og    = rc / 18;
        int co = og * 16 + (lane & 15);
        int k0 = chunk * 32 + (lane >> 4) * 8;
        ushort v[8];
#pragma unroll
        for (int j = 0; j < 8; ++j) {
            int k = k0 + j, c = k & 63, n = k >> 6;
            float w = 0.f;
            if (co < 18)      w = w_p[(co * 64 + c) * 9 + n];
            else if (co < 27) w = w_m[((co - 18) * 64 + c) * 9 + n];
            v[j] = f2bf(w);
        }
        ((uint4*)womf)[ii] = *(uint4*)v;
    }
}

// ---------------- Kernel 2: offsets (MFMA) + sampling + main GEMM -----------
// 256 threads = 4 waves, 16 consecutive pixels. Window channel-last in LDS,
// octet slot rotated by pos: channel-octet g stored at slot (g+pos)&7.
__global__ __launch_bounds__(256, 4) void kdeform(
    const ushort* __restrict__ xt,
    const ushort* __restrict__ wbf, const ushort* __restrict__ womf,
    const float* __restrict__ b_p, const float* __restrict__ b_m,
    ushort* __restrict__ outp)          // (B, 64, H, W) bf16
{
    __shared__ ushort sWin[NPOS * 64];  // 21504 B
    __shared__ ushort sXF[9216];        // 18432 B x_s fragments
    __shared__ float4 sG[9][16];        // 2304 B
    __shared__ uint   sPos[9][16];      // 576 B  packed window corner positions
    __shared__ uint   sOg[9][16];       // 576 B  packed global coords (fallback)
    __shared__ float  sOM[32][17];      // 2176 B
    __shared__ int    sFlag;

    int t    = threadIdx.x;
    int pix0 = blockIdx.x * 16;
    int b    = pix0 / PLANE;
    int rem  = pix0 - b * PLANE;
    int h    = rem / HW;
    int w0   = rem - h * HW;            // multiple of 16
    int rbase = min(max(h - 2, 0), H2 - WR);
    int wbase = min(max(w0 - 2, 0), 196 - WC);   // window cols fit < W2
    if (t == 0) sFlag = 0;

    const ushort* xtb = xt + (size_t)(b * H2) * W2 * 64;

    // ---- phase S: stage 7x24 window, channel-last, rotated octets ----
    {
        const uint4* gsrc = (const uint4*)(xtb + ((size_t)rbase * W2 + wbase) * 64);
#pragma unroll
        for (int it = 0; it < 6; ++it) {
            int idx = t + 256 * it;      // 0..1343 = 168 pos x 8 slots
            if (idx < NPOS * 8) {
                int pos = idx >> 3, s = idx & 7;
                int g   = (s - pos) & 7;
                int r   = (pos * 2731) >> 16;    // pos/24
                int cc  = pos - r * WC;
                *(uint4*)&sWin[pos * 64 + s * 8] = gsrc[((r * W2 + cc) << 3) + g];
            }
        }
    }
    __syncthreads();

    // ---- phase B: offset+mask conv, B-operand read directly from window ----
    if (t < 128) {
        int lane = t & 63, og = t >> 6;
        int sub  = lane >> 4;
        int hr   = h - rbase;
        int wrp  = w0 - wbase + (lane & 15);
        f32x4 acc = {0.f, 0.f, 0.f, 0.f};
#pragma unroll
        for (int chunk = 0; chunk < 18; ++chunk) {
            bf16x8 a = *(const bf16x8*)&womf[((og * 18 + chunk) * 64 + lane) * 8];
            int n  = chunk >> 1;
            int dy = n / 3, dx = n - dy * 3;
            int pos  = (hr + dy) * WC + wrp + dx;
            int slot = ((chunk & 1) * 4 + sub + pos) & 7;
            bf16x8 bb = *(const bf16x8*)&sWin[pos * 64 + slot * 8];
            acc = __builtin_amdgcn_mfma_f32_16x16x32_bf16(a, bb, acc, 0, 0, 0);
        }
        int col = lane & 15, row0 = sub * 4;
#pragma unroll
        for (int r = 0; r < 4; ++r) sOM[og * 16 + row0 + r][col] = acc[r];
    }
    __syncthreads();

    // ---- phase C: per-(pixel,tap) corner positions + bilinear*mask weights --
    if (t < 144) {
        int pp = t & 15, n = t >> 4;
        float offy = sOM[n][pp]      + b_p[n];
        float offx = sOM[9 + n][pp]  + b_p[9 + n];
        float mr   = sOM[18 + n][pp] + b_m[n];
        float m = 1.f / (1.f + __expf(-mr));
        int dy = n / 3, dx = n - dy * 3;
        float py = (float)(h + dy) + offy;           // padded coords
        float px = (float)(w0 + pp + dx) + offx;
        float fy = floorf(py), fx = floorf(px);
        float qy0 = fminf(fmaxf(fy,       0.f), 193.f);
        float qy1 = fminf(fmaxf(fy + 1.f, 0.f), 193.f);
        float qx0 = fminf(fmaxf(fx,       0.f), 193.f);
        float qx1 = fminf(fmaxf(fx + 1.f, 0.f), 193.f);
        float pyc = fminf(fmaxf(py, 0.f), 193.f);
        float pxc = fminf(fmaxf(px, 0.f), 193.f);
        float ay = 1.f + qy0 - pyc, by = 1.f - (qy1 - pyc);
        float ax = 1.f + qx0 - pxc, bx = 1.f - (qx1 - pxc);
        int ry0 = (int)qy0, ry1 = (int)qy1;
        int cx0 = (int)qx0, cx1 = (int)qx1;
        int xs  = cx1 - cx0;                          // 0 or 1
        sOg[n][pp] = (uint)(ry0 | (ry1 << 8) | (cx0 << 16) | (xs << 24));
        int p00 = (ry0 - rbase) * WC + (cx0 - wbase);
        int p10 = (ry1 - rbase) * WC + (cx0 - wbase);
        sPos[n][pp] = (uint)((p00 & 255) | (((p00 + xs) & 255) << 8)
                           | ((p10 & 255) << 16) | (((p10 + xs) & 255) << 24));
        sG[n][pp] = make_float4(ay * ax * m, ay * bx * m, by * ax * m, by * bx * m);
        if (ry0 < rbase || ry1 > rbase + (WR - 1) ||
            cx0 < wbase || cx1 > wbase + (WC - 1))
            atomicOr(&sFlag, 1);
    }
    __syncthreads();

    // ---- phase D: bilinear sampling, 8 channels per b128 read ----
    {
        int px  = t & 15, sub = t >> 4;
        int o8  = sub & 7;
        bool fb = (sFlag != 0);
#pragma unroll
        for (int it = 0; it < 5; ++it) {
            int item = sub + 16 * it;            // (n, octet) work item
            if (item >= 72) break;
            int n = item >> 3;
            float4 G = sG[n][px];
            bf16x8 a0, a1, c0, c1;
            if (!fb) {
                uint pk = sPos[n][px];
                int p00 = pk & 255, p01 = (pk >> 8) & 255;
                int p10 = (pk >> 16) & 255, p11 = pk >> 24;
                a0 = *(const bf16x8*)&sWin[p00 * 64 + ((o8 + p00) & 7) * 8];
                a1 = *(const bf16x8*)&sWin[p01 * 64 + ((o8 + p01) & 7) * 8];
                c0 = *(const bf16x8*)&sWin[p10 * 64 + ((o8 + p10) & 7) * 8];
                c1 = *(const bf16x8*)&sWin[p11 * 64 + ((o8 + p11) & 7) * 8];
            } else {
                uint gp = sOg[n][px];
                int ry0 = gp & 255, ry1 = (gp >> 8) & 255;
                int cx0 = (gp >> 16) & 255, xs = gp >> 24;
                const ushort* g0 = xtb + (size_t)(ry0 * W2 + cx0) * 64 + o8 * 8;
                const ushort* g1 = xtb + (size_t)(ry1 * W2 + cx0) * 64 + o8 * 8;
                a0 = *(const bf16x8*)g0;
                a1 = *(const bf16x8*)(g0 + xs * 64);
                c0 = *(const bf16x8*)g1;
                c1 = *(const bf16x8*)(g1 + xs * 64);
            }
            ushort pk8[8] __attribute__((aligned(16)));
#pragma unroll
            for (int j = 0; j < 8; ++j) {
                float v = G.x * bf2f((ushort)a0[j]) + G.y * bf2f((ushort)a1[j])
                        + G.z * bf2f((ushort)c0[j]) + G.w * bf2f((ushort)c1[j]);
                pk8[j] = f2bf(v);
            }
            int chunk = n * 2 + (o8 >> 2), s16 = o8 & 3;
            *(uint4*)&sXF[(chunk * 64 + s16 * 16 + (px ^ s16)) * 8] = *(uint4*)pk8;
        }
    }
    __syncthreads();

    // ---- phase E: main MFMA GEMM, store bf16 ----
    {
        int lane = t & 63, og = t >> 6;
        int sub = lane >> 4, pcol = lane & 15;
        f32x4 acc = {0.f, 0.f, 0.f, 0.f};
#pragma unroll
        for (int chunk = 0; chunk < 18; ++chunk) {
            bf16x8 a  = *(const bf16x8*)&wbf[((og * 18 + chunk) * 64 + lane) * 8];
            bf16x8 bb = *(const bf16x8*)&sXF[(chunk * 64 + sub * 16 + (pcol ^ sub)) * 8];
            acc = __builtin_amdgcn_mfma_f32_16x16x32_bf16(a, bb, acc, 0, 0, 0);
        }
        int row0 = sub * 4;
        ushort* ob = outp + ((size_t)(b * COUT + og * 16 + row0)) * PLANE + rem + pcol;
        ob[0]                 = f2bf(acc[0]);
        ob[(size_t)PLANE]     = f2bf(acc[1]);
        ob[2 * (size_t)PLANE] = f2bf(acc[2]);
        ob[3 * (size_t)PLANE] = f2bf(acc[3]);
    }
}

// ---------------- Kernel 3: per-(channel,slice) partial stats, no atomics ---
__global__ __launch_bounds__(256) void kstats(
    const ushort* __restrict__ outp, float* __restrict__ partial)
{
    int o  = blockIdx.x >> 3;
    int sl = blockIdx.x & 7;
    int t  = threadIdx.x;
    float s = 0.f, s2 = 0.f;
    for (int b = 0; b < NB; ++b) {
        const uint4* pl = (const uint4*)(outp + ((size_t)(b * COUT + o)) * PLANE
                                         + sl * (PLANE / 8));
        for (int i = t; i < PLANE / 64; i += 256) {   // 576 uint4 per slice
            uint4 v = pl[i];
            unsigned ua[4] = {v.x, v.y, v.z, v.w};
#pragma unroll
            for (int j = 0; j < 4; ++j) {
                float lo = __builtin_bit_cast(float, ua[j] << 16);
                float hi = __builtin_bit_cast(float, ua[j] & 0xffff0000u);
                s  += lo + hi;
                s2 += lo * lo + hi * hi;
            }
        }
    }
    __shared__ float rs[256], rs2[256];
    rs[t] = s; rs2[t] = s2;
    __syncthreads();
    for (int st = 128; st > 0; st >>= 1) {
        if (t < st) { rs[t] += rs[t + st]; rs2[t] += rs2[t + st]; }
        __syncthreads();
    }
    if (t == 0) {
        partial[o * 8 + sl]       = rs[0];
        partial[512 + o * 8 + sl] = rs2[0];
    }
}

// ---------------- Kernel 4: BN finalize + ReLU + 2x2 maxpool ----------------
__global__ __launch_bounds__(256) void kbnpool(
    const ushort* __restrict__ outp, const float* __restrict__ partial,
    const float* __restrict__ gamma, const float* __restrict__ beta,
    float* __restrict__ out)
{
    int i = blockIdx.x * 256 + threadIdx.x;   // 0..2359295 exact
    int wo  = i % 96;
    int tmp = i / 96;
    int ho  = tmp % 96; tmp /= 96;
    int o   = tmp % 64;
    int b   = tmp / 64;
    float s = 0.f, s2 = 0.f;
#pragma unroll
    for (int sl = 0; sl < 8; ++sl) {
        s  += partial[o * 8 + sl];
        s2 += partial[512 + o * 8 + sl];
    }
    float inv  = 1.f / (float)(NB * PLANE);
    float mean = s * inv;
    float var  = s2 * inv - mean * mean;
    float rsq  = rsqrtf(var + 1e-5f);
    float g  = gamma[o] * rsq;
    float bt = beta[o] - mean * g;
    const ushort* pl = outp + ((size_t)(b * COUT + o)) * PLANE + (2 * ho) * HW + 2 * wo;
    unsigned u01 = *(const unsigned*)pl;
    unsigned u23 = *(const unsigned*)(pl + HW);
    float y00 = fmaxf(g * bf2f((ushort)(u01 & 0xffff)) + bt, 0.f);
    float y01 = fmaxf(g * bf2f((ushort)(u01 >> 16))    + bt, 0.f);
    float y10 = fmaxf(g * bf2f((ushort)(u23 & 0xffff)) + bt, 0.f);
    float y11 = fmaxf(g * bf2f((ushort)(u23 >> 16))    + bt, 0.f);
    out[i] = fmaxf(fmaxf(y00, y01), fmaxf(y10, y11));
}

// ---------------- launcher --------------------------------------------------
extern "C" void kernel_launch(void* const* d_in, const int* in_sizes, int n_in,
                              void* d_out, int out_size, void* d_ws, size_t ws_size,
                              hipStream_t stream)
{
    const float* x      = (const float*)d_in[0];
    const float* w_p    = (const float*)d_in[1];
    const float* b_p    = (const float*)d_in[2];
    const float* w_m    = (const float*)d_in[3];
    const float* b_m    = (const float*)d_in[4];
    const float* w_conv = (const float*)d_in[5];
    const float* gamma  = (const float*)d_in[6];
    const float* beta   = (const float*)d_in[7];
    float* out = (float*)d_out;

    char* ws = (char*)d_ws;
    ushort* xt      = (ushort*)ws;                    // 4*194*200*64*2 = 19,865,600 B
    ushort* outp    = (ushort*)(ws + 19865600);       // 18,874,368 B
    float*  partial = (float*)(ws + 38739968);        // 4096 B
    ushort* wbf     = (ushort*)(ws + 38744064);       // 73,728 B
    ushort* womf    = (ushort*)(ws + 38817792);       // 36,864 B

    kpadprep<<<NB * H2 + 27, 256, 0, stream>>>(x, w_conv, w_p, w_m, xt, wbf, womf);
    kdeform<<<NPIX / 16, 256, 0, stream>>>(xt, wbf, womf, b_p, b_m, outp);
    kstats<<<512, 256, 0, stream>>>(outp, partial);
    kbnpool<<<(NB * COUT * 96 * 96) / 256, 256, 0, stream>>>(outp, partial, gamma, beta, out);
}

// Round 7
// 181.886 us; speedup vs baseline: 3.9843x; 1.0559x over previous
//
#include <hip/hip_runtime.h>
#include <hip/hip_bf16.h>
#include <math.h>

#define HW     192
#define PLANE  (HW*HW)        // 36864
#define CIN    64
#define COUT   64
#define NB     4
#define NPIX   (NB*PLANE)     // 147456
#define H2     194
#define W2     200
#define WR     7
#define WC     21
#define NPOS   (WR*WC)        // 147

typedef __attribute__((ext_vector_type(8))) short bf16x8;
typedef __attribute__((ext_vector_type(4))) float f32x4;
typedef __attribute__((ext_vector_type(2))) float f32x2;

static __device__ __forceinline__ ushort f2bf(float f) {
    __hip_bfloat16 h = __float2bfloat16(f);
    return __builtin_bit_cast(ushort, h);
}
static __device__ __forceinline__ float bf2f(ushort u) {
    return __builtin_bit_cast(float, ((unsigned)u) << 16);
}
static __device__ __forceinline__ f32x2 up2(unsigned u) {   // (lo bf16, hi bf16)
    f32x2 r;
    r.x = __builtin_bit_cast(float, u << 16);
    r.y = __builtin_bit_cast(float, u & 0xffff0000u);
    return r;
}

// ---------------- Kernel 1: transpose x -> channel-last padded bf16 + weights
// xt[b][y][col][c]: y 0..193, col 0..199, c 0..63; data at y,col in [1..192]
__global__ __launch_bounds__(256) void kpadprep(
    const float* __restrict__ x,
    const float* __restrict__ wc, const float* __restrict__ w_p,
    const float* __restrict__ w_m,
    ushort* __restrict__ xt, ushort* __restrict__ wbf, ushort* __restrict__ womf)
{
    int blk = blockIdx.x;
    int t   = threadIdx.x;
    if (blk < NB * H2 * 2) {                 // transpose path: one (b, y, col-half)
        __shared__ ushort sT[100 * 72];      // [lcol][c], col-stride 72
        int half = blk & 1;
        int y    = (blk >> 1) % H2;
        int b    = (blk >> 1) / H2;
        int col0 = half * 100;
        const float* xb = x + (size_t)b * CIN * PLANE;
        bool yok = (y >= 1 && y <= HW);
#pragma unroll
        for (int it = 0; it < 13; ++it) {
            int idx = t + 256 * it;          // 0..3199 = 32 c-pairs x 100 cols
            if (idx < 3200) {
                int cp   = (idx * 5243) >> 19;   // idx/100
                int lcol = idx - cp * 100;
                int col  = col0 + lcol;
                int c    = cp * 2;
                float v0 = 0.f, v1 = 0.f;
                if (yok && col >= 1 && col <= HW) {
                    const float* s0 = xb + (size_t)c * PLANE + (y - 1) * HW + (col - 1);
                    v0 = s0[0]; v1 = s0[PLANE];
                }
                *(unsigned*)&sT[lcol * 72 + c] =
                    (unsigned)f2bf(v0) | ((unsigned)f2bf(v1) << 16);
            }
        }
        __syncthreads();
        uint4* dst = (uint4*)(xt + ((size_t)(b * H2 + y) * W2) * 64);
#pragma unroll
        for (int it = 0; it < 4; ++it) {
            int idx = t + 256 * it;          // 0..799 = 100 cols x 8 octets
            if (idx < 800) {
                int lcol = idx >> 3, g = idx & 7;
                dst[(col0 + lcol) * 8 + g] = *(uint4*)&sT[lcol * 72 + g * 8];
            }
        }
        return;
    }
    // weight prep path (27 blocks). k-order: k = n*64 + c
    int i = (blk - NB * H2 * 2) * 256 + t;   // 0..6911
    if (i < 4608) {
        int lane  = i & 63;
        int rc    = i >> 6;
        int chunk = rc % 18;
        int og    = rc / 18;
        int o  = og * 16 + (lane & 15);
        int k0 = chunk * 32 + (lane >> 4) * 8;
        ushort v[8];
#pragma unroll
        for (int j = 0; j < 8; ++j) {
            int k = k0 + j, c = k & 63, n = k >> 6;
            v[j] = f2bf(wc[o * 576 + c * 9 + n]);
        }
        ((uint4*)wbf)[i] = *(uint4*)v;
    } else if (i < 6912) {
        int ii    = i - 4608;
        int lane  = ii & 63;
        int rc    = ii >> 6;
        int chunk = rc % 18;
        int og    = rc / 18;
        int co = og * 16 + (lane & 15);
        int k0 = chunk * 32 + (lane >> 4) * 8;
        ushort v[8];
#pragma unroll
        for (int j = 0; j < 8; ++j) {
            int k = k0 + j, c = k & 63, n = k >> 6;
            float w = 0.f;
            if (co < 18)      w = w_p[(co * 64 + c) * 9 + n];
            else if (co < 27) w = w_m[((co - 18) * 64 + c) * 9 + n];
            v[j] = f2bf(w);
        }
        ((uint4*)womf)[ii] = *(uint4*)v;
    }
}

// ---------------- Kernel 2: offsets (MFMA) + sampling + main GEMM -----------
// 256 threads = 4 waves, 16 consecutive pixels. Window channel-last in LDS,
// octet slot rotated by pos. LDS budget 40708 B -> 4 blocks/CU.
__global__ __launch_bounds__(256, 4) void kdeform(
    const ushort* __restrict__ xt,
    const ushort* __restrict__ wbf, const ushort* __restrict__ womf,
    const float* __restrict__ b_p, const float* __restrict__ b_m,
    ushort* __restrict__ outp)          // (B, 64, H, W) bf16
{
    __shared__ __align__(16) char smem[40708];
    ushort* sWin = (ushort*)smem;                          // 18816 B (147*128)
    ushort* sXF  = (ushort*)(smem + 18816);                // 18432 B
    float (*sOM)[17] = (float(*)[17])(smem + 18816);       // 2176 B overlay on sXF
    float4 (*sG)[16] = (float4(*)[16])(smem + 37248);      // 2304 B
    uint (*sPos)[16] = (uint(*)[16])(smem + 39552);        // 576 B
    uint (*sOg)[16]  = (uint(*)[16])(smem + 40128);        // 576 B
    int* sFlag = (int*)(smem + 40704);

    int t    = threadIdx.x;
    int pix0 = blockIdx.x * 16;
    int b    = pix0 / PLANE;
    int rem  = pix0 - b * PLANE;
    int h    = rem / HW;
    int w0   = rem - h * HW;            // multiple of 16
    int rbase = min(max(h - 2, 0), H2 - WR);
    int wbase = min(max(w0 - 2, 0), W2 - WC - 4);   // keep right margin in-image
    if (t == 0) *sFlag = 0;

    const ushort* xtb = xt + (size_t)(b * H2) * W2 * 64;

    // ---- phase S: stage 7x21 window, channel-last, rotated octets ----
    {
        const uint4* gsrc = (const uint4*)(xtb + ((size_t)rbase * W2 + wbase) * 64);
#pragma unroll
        for (int it = 0; it < 5; ++it) {
            int idx = t + 256 * it;      // 0..1175 = 147 pos x 8 slots
            if (idx < NPOS * 8) {
                int pos = idx >> 3, s = idx & 7;
                int g   = (s - pos) & 7;
                int r   = (pos * 3121) >> 16;    // pos/21 for pos<1000
                int cc  = pos - r * WC;
                *(uint4*)&sWin[pos * 64 + s * 8] = gsrc[((r * W2 + cc) << 3) + g];
            }
        }
    }
    __syncthreads();

    // ---- phase B: offset+mask conv, B-operand read directly from window ----
    if (t < 128) {
        int lane = t & 63, og = t >> 6;
        int sub  = lane >> 4;
        int hr   = h - rbase;
        int wrp  = w0 - wbase + (lane & 15);
        f32x4 acc = {0.f, 0.f, 0.f, 0.f};
#pragma unroll
        for (int chunk = 0; chunk < 18; ++chunk) {
            bf16x8 a = *(const bf16x8*)&womf[((og * 18 + chunk) * 64 + lane) * 8];
            int n  = chunk >> 1;
            int dy = n / 3, dx = n - dy * 3;
            int pos  = (hr + dy) * WC + wrp + dx;
            int slot = ((chunk & 1) * 4 + sub + pos) & 7;
            bf16x8 bb = *(const bf16x8*)&sWin[pos * 64 + slot * 8];
            acc = __builtin_amdgcn_mfma_f32_16x16x32_bf16(a, bb, acc, 0, 0, 0);
        }
        int col = lane & 15, row0 = sub * 4;
#pragma unroll
        for (int r = 0; r < 4; ++r) sOM[og * 16 + row0 + r][col] = acc[r];
    }
    __syncthreads();

    // ---- phase C: per-(pixel,tap) corner positions + bilinear*mask weights --
    uint pkC = 0, ogC = 0; float4 gC;
    if (t < 144) {
        int pp = t & 15, n = t >> 4;
        float offy = sOM[n][pp]      + b_p[n];
        float offx = sOM[9 + n][pp]  + b_p[9 + n];
        float mr   = sOM[18 + n][pp] + b_m[n];
        float m = 1.f / (1.f + __expf(-mr));
        int dy = n / 3, dx = n - dy * 3;
        float py = (float)(h + dy) + offy;           // padded coords
        float px = (float)(w0 + pp + dx) + offx;
        float fy = floorf(py), fx = floorf(px);
        float qy0 = fminf(fmaxf(fy,       0.f), 193.f);
        float qy1 = fminf(fmaxf(fy + 1.f, 0.f), 193.f);
        float qx0 = fminf(fmaxf(fx,       0.f), 193.f);
        float qx1 = fminf(fmaxf(fx + 1.f, 0.f), 193.f);
        float pyc = fminf(fmaxf(py, 0.f), 193.f);
        float pxc = fminf(fmaxf(px, 0.f), 193.f);
        float ay = 1.f + qy0 - pyc, by = 1.f - (qy1 - pyc);
        float ax = 1.f + qx0 - pxc, bx = 1.f - (qx1 - pxc);
        int ry0 = (int)qy0, ry1 = (int)qy1;
        int cx0 = (int)qx0, cx1 = (int)qx1;
        int xs  = cx1 - cx0;                          // 0 or 1
        ogC = (uint)(ry0 | (ry1 << 8) | (cx0 << 16) | (xs << 24));
        int p00 = (ry0 - rbase) * WC + (cx0 - wbase);
        int p10 = (ry1 - rbase) * WC + (cx0 - wbase);
        pkC = (uint)((p00 & 255) | (((p00 + xs) & 255) << 8)
                   | ((p10 & 255) << 16) | (((p10 + xs) & 255) << 24));
        gC = make_float4(ay * ax * m, ay * bx * m, by * ax * m, by * bx * m);
        if (ry0 < rbase || ry1 > rbase + (WR - 1) ||
            cx0 < wbase || cx1 > wbase + (WC - 1))
            atomicOr(sFlag, 1);
    }
    __syncthreads();          // sOM dead; sXF region reusable
    if (t < 144) {
        int pp = t & 15, n = t >> 4;
        sOg[n][pp]  = ogC;
        sPos[n][pp] = pkC;
        sG[n][pp]   = gC;
    }
    __syncthreads();

    // ---- phase D: bilinear sampling, 8 channels per b128, packed fp32 math --
    {
        int px  = t & 15, sub = t >> 4;
        int o8  = sub & 7;
        bool fb = (*sFlag != 0);
#pragma unroll
        for (int it = 0; it < 5; ++it) {
            int item = sub + 16 * it;            // (n, octet) work item
            if (item >= 72) break;
            int n = item >> 3;
            float4 G = sG[n][px];
            uint4 A0, A1, C0, C1;
            if (!fb) {
                uint pk = sPos[n][px];
                int p00 = pk & 255, p01 = (pk >> 8) & 255;
                int p10 = (pk >> 16) & 255, p11 = pk >> 24;
                A0 = *(const uint4*)&sWin[p00 * 64 + ((o8 + p00) & 7) * 8];
                A1 = *(const uint4*)&sWin[p01 * 64 + ((o8 + p01) & 7) * 8];
                C0 = *(const uint4*)&sWin[p10 * 64 + ((o8 + p10) & 7) * 8];
                C1 = *(const uint4*)&sWin[p11 * 64 + ((o8 + p11) & 7) * 8];
            } else {
                uint gp = sOg[n][px];
                int ry0 = gp & 255, ry1 = (gp >> 8) & 255;
                int cx0 = (gp >> 16) & 255, xs = gp >> 24;
                const ushort* g0 = xtb + (size_t)(ry0 * W2 + cx0) * 64 + o8 * 8;
                const ushort* g1 = xtb + (size_t)(ry1 * W2 + cx0) * 64 + o8 * 8;
                A0 = *(const uint4*)g0;
                A1 = *(const uint4*)(g0 + xs * 64);
                C0 = *(const uint4*)g1;
                C1 = *(const uint4*)(g1 + xs * 64);
            }
            unsigned ua0[4] = {A0.x, A0.y, A0.z, A0.w};
            unsigned ua1[4] = {A1.x, A1.y, A1.z, A1.w};
            unsigned uc0[4] = {C0.x, C0.y, C0.z, C0.w};
            unsigned uc1[4] = {C1.x, C1.y, C1.z, C1.w};
            ushort pk8[8] __attribute__((aligned(16)));
#pragma unroll
            for (int q = 0; q < 4; ++q) {
                f32x2 v = G.x * up2(ua0[q]) + G.y * up2(ua1[q])
                        + G.z * up2(uc0[q]) + G.w * up2(uc1[q]);
                pk8[2 * q]     = f2bf(v.x);
                pk8[2 * q + 1] = f2bf(v.y);
            }
            int chunk = n * 2 + (o8 >> 2), s16 = o8 & 3;
            *(uint4*)&sXF[(chunk * 64 + s16 * 16 + (px ^ s16)) * 8] = *(uint4*)pk8;
        }
    }
    __syncthreads();

    // ---- phase E: main MFMA GEMM, store bf16 ----
    {
        int lane = t & 63, og = t >> 6;
        int sub = lane >> 4, pcol = lane & 15;
        f32x4 acc = {0.f, 0.f, 0.f, 0.f};
#pragma unroll
        for (int chunk = 0; chunk < 18; ++chunk) {
            bf16x8 a  = *(const bf16x8*)&wbf[((og * 18 + chunk) * 64 + lane) * 8];
            bf16x8 bb = *(const bf16x8*)&sXF[(chunk * 64 + sub * 16 + (pcol ^ sub)) * 8];
            acc = __builtin_amdgcn_mfma_f32_16x16x32_bf16(a, bb, acc, 0, 0, 0);
        }
        int row0 = sub * 4;
        ushort* ob = outp + ((size_t)(b * COUT + og * 16 + row0)) * PLANE + rem + pcol;
        ob[0]                 = f2bf(acc[0]);
        ob[(size_t)PLANE]     = f2bf(acc[1]);
        ob[2 * (size_t)PLANE] = f2bf(acc[2]);
        ob[3 * (size_t)PLANE] = f2bf(acc[3]);
    }
}

// ---------------- Kernel 3: per-(channel,slice) partial stats, no atomics ---
__global__ __launch_bounds__(256) void kstats(
    const ushort* __restrict__ outp, float* __restrict__ partial)
{
    int o  = blockIdx.x >> 3;
    int sl = blockIdx.x & 7;
    int t  = threadIdx.x;
    float s = 0.f, s2 = 0.f;
    for (int b = 0; b < NB; ++b) {
        const uint4* pl = (const uint4*)(outp + ((size_t)(b * COUT + o)) * PLANE
                                         + sl * (PLANE / 8));
        for (int i = t; i < PLANE / 64; i += 256) {   // 576 uint4 per slice
            uint4 v = pl[i];
            unsigned ua[4] = {v.x, v.y, v.z, v.w};
#pragma unroll
            for (int j = 0; j < 4; ++j) {
                float lo = __builtin_bit_cast(float, ua[j] << 16);
                float hi = __builtin_bit_cast(float, ua[j] & 0xffff0000u);
                s  += lo + hi;
                s2 += lo * lo + hi * hi;
            }
        }
    }
    __shared__ float rs[256], rs2[256];
    rs[t] = s; rs2[t] = s2;
    __syncthreads();
    for (int st = 128; st > 0; st >>= 1) {
        if (t < st) { rs[t] += rs[t + st]; rs2[t] += rs2[t + st]; }
        __syncthreads();
    }
    if (t == 0) {
        partial[o * 8 + sl]       = rs[0];
        partial[512 + o * 8 + sl] = rs2[0];
    }
}

// ---------------- Kernel 4: BN finalize + ReLU + 2x2 maxpool ----------------
__global__ __launch_bounds__(256) void kbnpool(
    const ushort* __restrict__ outp, const float* __restrict__ partial,
    const float* __restrict__ gamma, const float* __restrict__ beta,
    float* __restrict__ out)
{
    int i = blockIdx.x * 256 + threadIdx.x;   // 0..2359295 exact
    int wo  = i % 96;
    int tmp = i / 96;
    int ho  = tmp % 96; tmp /= 96;
    int o   = tmp % 64;
    int b   = tmp / 64;
    float s = 0.f, s2 = 0.f;
#pragma unroll
    for (int sl = 0; sl < 8; ++sl) {
        s  += partial[o * 8 + sl];
        s2 += partial[512 + o * 8 + sl];
    }
    float inv  = 1.f / (float)(NB * PLANE);
    float mean = s * inv;
    float var  = s2 * inv - mean * mean;
    float rsq  = rsqrtf(var + 1e-5f);
    float g  = gamma[o] * rsq;
    float bt = beta[o] - mean * g;
    const ushort* pl = outp + ((size_t)(b * COUT + o)) * PLANE + (2 * ho) * HW + 2 * wo;
    unsigned u01 = *(const unsigned*)pl;
    unsigned u23 = *(const unsigned*)(pl + HW);
    float y00 = fmaxf(g * bf2f((ushort)(u01 & 0xffff)) + bt, 0.f);
    float y01 = fmaxf(g * bf2f((ushort)(u01 >> 16))    + bt, 0.f);
    float y10 = fmaxf(g * bf2f((ushort)(u23 & 0xffff)) + bt, 0.f);
    float y11 = fmaxf(g * bf2f((ushort)(u23 >> 16))    + bt, 0.f);
    out[i] = fmaxf(fmaxf(y00, y01), fmaxf(y10, y11));
}

// ---------------- launcher --------------------------------------------------
extern "C" void kernel_launch(void* const* d_in, const int* in_sizes, int n_in,
                              void* d_out, int out_size, void* d_ws, size_t ws_size,
                              hipStream_t stream)
{
    const float* x      = (const float*)d_in[0];
    const float* w_p    = (const float*)d_in[1];
    const float* b_p    = (const float*)d_in[2];
    const float* w_m    = (const float*)d_in[3];
    const float* b_m    = (const float*)d_in[4];
    const float* w_conv = (const float*)d_in[5];
    const float* gamma  = (const float*)d_in[6];
    const float* beta   = (const float*)d_in[7];
    float* out = (float*)d_out;

    char* ws = (char*)d_ws;
    ushort* xt      = (ushort*)ws;                    // 4*194*200*64*2 = 19,865,600 B
    ushort* outp    = (ushort*)(ws + 19865600);       // 18,874,368 B
    float*  partial = (float*)(ws + 38739968);        // 4096 B
    ushort* wbf     = (ushort*)(ws + 38744064);       // 73,728 B
    ushort* womf    = (ushort*)(ws + 38817792);       // 36,864 B

    kpadprep<<<NB * H2 * 2 + 27, 256, 0, stream>>>(x, w_conv, w_p, w_m, xt, wbf, womf);
    kdeform<<<NPIX / 16, 256, 0, stream>>>(xt, wbf, womf, b_p, b_m, outp);
    kstats<<<512, 256, 0, stream>>>(outp, partial);
    kbnpool<<<(NB * COUT * 96 * 96) / 256, 256, 0, stream>>>(outp, partial, gamma, beta, out);
}

// Round 9
// 180.303 us; speedup vs baseline: 4.0193x; 1.0088x over previous
//
#include <hip/hip_runtime.h>
#include <hip/hip_bf16.h>
#include <math.h>

#define HW     192
#define PLANE  (HW*HW)        // 36864
#define CIN    64
#define COUT   64
#define NB     4
#define NPIX   (NB*PLANE)     // 147456
#define H2     194
#define W2     200
#define WR     7
#define WC     21
#define NPOS   (WR*WC)        // 147

typedef __attribute__((ext_vector_type(8))) short bf16x8;
typedef __attribute__((ext_vector_type(4))) float f32x4;
typedef __attribute__((ext_vector_type(2))) float f32x2;

static __device__ __forceinline__ ushort f2bf(float f) {
    __hip_bfloat16 h = __float2bfloat16(f);
    return __builtin_bit_cast(ushort, h);
}
static __device__ __forceinline__ float bf2f(ushort u) {
    return __builtin_bit_cast(float, ((unsigned)u) << 16);
}
static __device__ __forceinline__ f32x2 up2(unsigned u) {   // (lo bf16, hi bf16)
    f32x2 r;
    r.x = __builtin_bit_cast(float, u << 16);
    r.y = __builtin_bit_cast(float, u & 0xffff0000u);
    return r;
}

// ---------------- Kernel 1: transpose x -> channel-last padded bf16 + weights
// xt[b][y][col][c]: y 0..193, col 0..199, c 0..63; data at y,col in [1..192]
__global__ __launch_bounds__(256) void kpadprep(
    const float* __restrict__ x,
    const float* __restrict__ wc, const float* __restrict__ w_p,
    const float* __restrict__ w_m,
    ushort* __restrict__ xt, ushort* __restrict__ wbf, ushort* __restrict__ womf)
{
    int blk = blockIdx.x;
    int t   = threadIdx.x;
    if (blk < NB * H2) {                     // transpose path: one (b, y) row
        __shared__ ushort sT[W2 * 72];       // [col][c], col-stride 72 (28800 B)
        int b = blk / H2, y = blk % H2;
        bool yok = (y >= 1 && y <= HW);
        const float* xb = x + (size_t)b * CIN * PLANE + (size_t)(y - 1) * HW;
        // zero-fill cols {0, 193..199}
        {
            int zi  = t >> 5;
            int col = (zi == 0) ? 0 : 192 + zi;
            *(unsigned*)&sT[col * 72 + (t & 31) * 2] = 0;
        }
        // aligned float4 quads: cols 4q+1..4q+4 <- x[row][4q..4q+3]
#pragma unroll
        for (int it = 0; it < 6; ++it) {
            int idx = t + 256 * it;          // 0..1535 = 32 c-pairs x 48 quads
            int cp  = idx / 48;
            int q   = idx - cp * 48;
            int c   = cp * 2;
            float4 v0 = make_float4(0.f, 0.f, 0.f, 0.f), v1 = v0;
            if (yok) {
                v0 = *(const float4*)(xb + (size_t)c * PLANE + 4 * q);
                v1 = *(const float4*)(xb + (size_t)(c + 1) * PLANE + 4 * q);
            }
            float a0[4] = {v0.x, v0.y, v0.z, v0.w};
            float a1[4] = {v1.x, v1.y, v1.z, v1.w};
#pragma unroll
            for (int j = 0; j < 4; ++j)
                *(unsigned*)&sT[(4 * q + 1 + j) * 72 + c] =
                    (unsigned)f2bf(a0[j]) | ((unsigned)f2bf(a1[j]) << 16);
        }
        __syncthreads();
        uint4* dst = (uint4*)(xt + ((size_t)(b * H2 + y) * W2) * 64);
#pragma unroll
        for (int it = 0; it < 7; ++it) {
            int idx = t + 256 * it;          // 0..1599 = 200 cols x 8 octets
            if (idx < 1600) {
                int col = idx >> 3, g = idx & 7;
                dst[col * 8 + g] = *(uint4*)&sT[col * 72 + g * 8];
            }
        }
        return;
    }
    // weight prep path (27 blocks). k-order: k = n*64 + c
    int i = (blk - NB * H2) * 256 + t;       // 0..6911
    if (i < 4608) {
        int lane  = i & 63;
        int rc    = i >> 6;
        int chunk = rc % 18;
        int og    = rc / 18;
        int o  = og * 16 + (lane & 15);
        int k0 = chunk * 32 + (lane >> 4) * 8;
        ushort v[8];
#pragma unroll
        for (int j = 0; j < 8; ++j) {
            int k = k0 + j, c = k & 63, n = k >> 6;
            v[j] = f2bf(wc[o * 576 + c * 9 + n]);
        }
        ((uint4*)wbf)[i] = *(uint4*)v;
    } else if (i < 6912) {
        int ii    = i - 4608;
        int lane  = ii & 63;
        int rc    = ii >> 6;
        int chunk = rc % 18;
        int og    = rc / 18;
        int co = og * 16 + (lane & 15);
        int k0 = chunk * 32 + (lane >> 4) * 8;
        ushort v[8];
#pragma unroll
        for (int j = 0; j < 8; ++j) {
            int k = k0 + j, c = k & 63, n = k >> 6;
            float w = 0.f;
            if (co < 18)      w = w_p[(co * 64 + c) * 9 + n];
            else if (co < 27) w = w_m[((co - 18) * 64 + c) * 9 + n];
            v[j] = f2bf(w);
        }
        ((uint4*)womf)[ii] = *(uint4*)v;
    }
}

// ---------------- Kernel 2: offsets (MFMA) + sampling + main GEMM -----------
// 256 threads = 4 waves, 16 consecutive pixels. Window channel-last in LDS,
// octet slot rotated by pos. LDS 40708 B -> 4 blocks/CU.
__global__ __launch_bounds__(256, 4) void kdeform(
    const ushort* __restrict__ xt,
    const ushort* __restrict__ wbf, const ushort* __restrict__ womf,
    const float* __restrict__ b_p, const float* __restrict__ b_m,
    ushort* __restrict__ outp)          // (B, 64, H, W) bf16
{
    __shared__ __align__(16) char smem[40708];
    ushort* sWin = (ushort*)smem;                          // 18816 B (147*128)
    ushort* sXF  = (ushort*)(smem + 18816);                // 18432 B
    float (*sOMa)[17] = (float(*)[17])(smem + 18816);          // 2176 B overlay
    float (*sOMb)[17] = (float(*)[17])(smem + 18816 + 2176);   // 2176 B overlay
    float4 (*sG)[16] = (float4(*)[16])(smem + 37248);      // 2304 B
    uint (*sPos)[16] = (uint(*)[16])(smem + 39552);        // 576 B
    uint (*sOg)[16]  = (uint(*)[16])(smem + 40128);        // 576 B
    int* sFlag = (int*)(smem + 40704);

    int t    = threadIdx.x;
    int pix0 = blockIdx.x * 16;
    int b    = pix0 / PLANE;
    int rem  = pix0 - b * PLANE;
    int h    = rem / HW;
    int w0   = rem - h * HW;            // multiple of 16
    int rbase = min(max(h - 2, 0), H2 - WR);
    int wbase = min(max(w0 - 2, 0), W2 - WC - 4);   // keep right margin in-image
    if (t == 0) *sFlag = 0;

    const ushort* xtb = xt + (size_t)(b * H2) * W2 * 64;

    // ---- phase S: stage 7x21 window, channel-last, rotated octets ----
    {
        const uint4* gsrc = (const uint4*)(xtb + ((size_t)rbase * W2 + wbase) * 64);
#pragma unroll
        for (int it = 0; it < 5; ++it) {
            int idx = t + 256 * it;      // 0..1175 = 147 pos x 8 slots
            if (idx < NPOS * 8) {
                int pos = idx >> 3, s = idx & 7;
                int g   = (s - pos) & 7;
                int r   = (pos * 3121) >> 16;    // pos/21 for pos<1000
                int cc  = pos - r * WC;
                *(uint4*)&sWin[pos * 64 + s * 8] = gsrc[((r * W2 + cc) << 3) + g];
            }
        }
    }
    __syncthreads();

    // ---- phase B: offset+mask conv, all 4 waves (2 og x 2 k-halves) ----
    {
        int lane = t & 63;
        int wv   = t >> 6;
        int og   = wv & 1;
        int half = wv >> 1;             // chunks half*9 .. half*9+8
        int sub  = lane >> 4;
        int hr   = h - rbase;
        int wrp  = w0 - wbase + (lane & 15);
        f32x4 acc = {0.f, 0.f, 0.f, 0.f};
#pragma unroll
        for (int cc = 0; cc < 9; ++cc) {
            int chunk = half * 9 + cc;
            bf16x8 a = *(const bf16x8*)&womf[((og * 18 + chunk) * 64 + lane) * 8];
            int n  = chunk >> 1;
            int dy = n / 3, dx = n - dy * 3;
            int pos  = (hr + dy) * WC + wrp + dx;
            int slot = ((chunk & 1) * 4 + sub + pos) & 7;
            bf16x8 bb = *(const bf16x8*)&sWin[pos * 64 + slot * 8];
            acc = __builtin_amdgcn_mfma_f32_16x16x32_bf16(a, bb, acc, 0, 0, 0);
        }
        int col = lane & 15, row0 = sub * 4;
        float (*dst)[17] = half ? sOMb : sOMa;
#pragma unroll
        for (int r = 0; r < 4; ++r) dst[og * 16 + row0 + r][col] = acc[r];
    }
    __syncthreads();

    // ---- phase C: corner positions + bilinear*mask weights ----
    uint pkC = 0, ogC = 0; float4 gC = make_float4(0.f, 0.f, 0.f, 0.f);
    if (t < 144) {
        int pp = t & 15, n = t >> 4;
        float offy = sOMa[n][pp]      + sOMb[n][pp]      + b_p[n];
        float offx = sOMa[9 + n][pp]  + sOMb[9 + n][pp]  + b_p[9 + n];
        float mr   = sOMa[18 + n][pp] + sOMb[18 + n][pp] + b_m[n];
        float m = 1.f / (1.f + __expf(-mr));
        int dy = n / 3, dx = n - dy * 3;
        float py = (float)(h + dy) + offy;           // padded coords
        float px = (float)(w0 + pp + dx) + offx;
        float fy = floorf(py), fx = floorf(px);
        float qy0 = fminf(fmaxf(fy,       0.f), 193.f);
        float qy1 = fminf(fmaxf(fy + 1.f, 0.f), 193.f);
        float qx0 = fminf(fmaxf(fx,       0.f), 193.f);
        float qx1 = fminf(fmaxf(fx + 1.f, 0.f), 193.f);
        float pyc = fminf(fmaxf(py, 0.f), 193.f);
        float pxc = fminf(fmaxf(px, 0.f), 193.f);
        float ay = 1.f + qy0 - pyc, by = 1.f - (qy1 - pyc);
        float ax = 1.f + qx0 - pxc, bx = 1.f - (qx1 - pxc);
        int ry0 = (int)qy0, ry1 = (int)qy1;
        int cx0 = (int)qx0, cx1 = (int)qx1;
        int xs  = cx1 - cx0;                          // 0 or 1
        ogC = (uint)(ry0 | (ry1 << 8) | (cx0 << 16) | (xs << 24));
        int p00 = (ry0 - rbase) * WC + (cx0 - wbase);
        int p10 = (ry1 - rbase) * WC + (cx0 - wbase);
        pkC = (uint)((p00 & 255) | (((p00 + xs) & 255) << 8)
                   | ((p10 & 255) << 16) | (((p10 + xs) & 255) << 24));
        gC = make_float4(ay * ax * m, ay * bx * m, by * ax * m, by * bx * m);
        if (ry0 < rbase || ry1 > rbase + (WR - 1) ||
            cx0 < wbase || cx1 > wbase + (WC - 1))
            atomicOr(sFlag, 1);
    }
    __syncthreads();          // sOM overlays dead; sXF region reusable
    if (t < 144) {
        int pp = t & 15, n = t >> 4;
        sOg[n][pp]  = ogC;
        sPos[n][pp] = pkC;
        sG[n][pp]   = gC;
    }
    __syncthreads();

    // ---- phase D: bilinear sampling, 8 channels per b128, packed fp32 math --
    {
        int px  = t & 15, sub = t >> 4;
        int o8  = sub & 7;
        bool fb = (*sFlag != 0);
#pragma unroll
        for (int it = 0; it < 5; ++it) {
            int item = sub + 16 * it;            // (n, octet) work item
            if (item >= 72) break;
            int n = item >> 3;
            float4 G = sG[n][px];
            uint4 A0, A1, C0, C1;
            if (!fb) {
                uint pk = sPos[n][px];
                int p00 = pk & 255, p01 = (pk >> 8) & 255;
                int p10 = (pk >> 16) & 255, p11 = pk >> 24;
                A0 = *(const uint4*)&sWin[p00 * 64 + ((o8 + p00) & 7) * 8];
                A1 = *(const uint4*)&sWin[p01 * 64 + ((o8 + p01) & 7) * 8];
                C0 = *(const uint4*)&sWin[p10 * 64 + ((o8 + p10) & 7) * 8];
                C1 = *(const uint4*)&sWin[p11 * 64 + ((o8 + p11) & 7) * 8];
            } else {
                uint gp = sOg[n][px];
                int ry0 = gp & 255, ry1 = (gp >> 8) & 255;
                int cx0 = (gp >> 16) & 255, xs = gp >> 24;
                const ushort* g0 = xtb + (size_t)(ry0 * W2 + cx0) * 64 + o8 * 8;
                const ushort* g1 = xtb + (size_t)(ry1 * W2 + cx0) * 64 + o8 * 8;
                A0 = *(const uint4*)g0;
                A1 = *(const uint4*)(g0 + xs * 64);
                C0 = *(const uint4*)g1;
                C1 = *(const uint4*)(g1 + xs * 64);
            }
            unsigned ua0[4] = {A0.x, A0.y, A0.z, A0.w};
            unsigned ua1[4] = {A1.x, A1.y, A1.z, A1.w};
            unsigned uc0[4] = {C0.x, C0.y, C0.z, C0.w};
            unsigned uc1[4] = {C1.x, C1.y, C1.z, C1.w};
            ushort pk8[8] __attribute__((aligned(16)));
#pragma unroll
            for (int q = 0; q < 4; ++q) {
                f32x2 v = G.x * up2(ua0[q]) + G.y * up2(ua1[q])
                        + G.z * up2(uc0[q]) + G.w * up2(uc1[q]);
                pk8[2 * q]     = f2bf(v.x);
                pk8[2 * q + 1] = f2bf(v.y);
            }
            int chunk = n * 2 + (o8 >> 2), s16 = o8 & 3;
            *(uint4*)&sXF[(chunk * 64 + s16 * 16 + (px ^ s16)) * 8] = *(uint4*)pk8;
        }
    }
    __syncthreads();

    // ---- phase E: main MFMA GEMM, store bf16 ----
    {
        int lane = t & 63, og = t >> 6;
        int sub = lane >> 4, pcol = lane & 15;
        f32x4 acc = {0.f, 0.f, 0.f, 0.f};
#pragma unroll
        for (int chunk = 0; chunk < 18; ++chunk) {
            bf16x8 a  = *(const bf16x8*)&wbf[((og * 18 + chunk) * 64 + lane) * 8];
            bf16x8 bb = *(const bf16x8*)&sXF[(chunk * 64 + sub * 16 + (pcol ^ sub)) * 8];
            acc = __builtin_amdgcn_mfma_f32_16x16x32_bf16(a, bb, acc, 0, 0, 0);
        }
        int row0 = sub * 4;
        ushort* ob = outp + ((size_t)(b * COUT + og * 16 + row0)) * PLANE + rem + pcol;
        ob[0]                 = f2bf(acc[0]);
        ob[(size_t)PLANE]     = f2bf(acc[1]);
        ob[2 * (size_t)PLANE] = f2bf(acc[2]);
        ob[3 * (size_t)PLANE] = f2bf(acc[3]);
    }
}

// ---------------- Kernel 3: per-(channel,slice) partial stats, no atomics ---
__global__ __launch_bounds__(256) void kstats(
    const ushort* __restrict__ outp, float* __restrict__ partial)
{
    int o  = blockIdx.x >> 3;
    int sl = blockIdx.x & 7;
    int t  = threadIdx.x;
    float s = 0.f, s2 = 0.f;
    for (int b = 0; b < NB; ++b) {
        const uint4* pl = (const uint4*)(outp + ((size_t)(b * COUT + o)) * PLANE
                                         + sl * (PLANE / 8));
        for (int i = t; i < PLANE / 64; i += 256) {   // 576 uint4 per slice
            uint4 v = pl[i];
            unsigned ua[4] = {v.x, v.y, v.z, v.w};
#pragma unroll
            for (int j = 0; j < 4; ++j) {
                float lo = __builtin_bit_cast(float, ua[j] << 16);
                float hi = __builtin_bit_cast(float, ua[j] & 0xffff0000u);
                s  += lo + hi;
                s2 += lo * lo + hi * hi;
            }
        }
    }
    __shared__ float rs[256], rs2[256];
    rs[t] = s; rs2[t] = s2;
    __syncthreads();
    for (int st = 128; st > 0; st >>= 1) {
        if (t < st) { rs[t] += rs[t + st]; rs2[t] += rs2[t + st]; }
        __syncthreads();
    }
    if (t == 0) {
        partial[o * 8 + sl]       = rs[0];
        partial[512 + o * 8 + sl] = rs2[0];
    }
}

// ---------------- Kernel 4: BN finalize + ReLU + 2x2 maxpool ----------------
__global__ __launch_bounds__(256) void kbnpool(
    const ushort* __restrict__ outp, const float* __restrict__ partial,
    const float* __restrict__ gamma, const float* __restrict__ beta,
    float* __restrict__ out)
{
    int i = blockIdx.x * 256 + threadIdx.x;   // 0..2359295 exact
    int wo  = i % 96;
    int tmp = i / 96;
    int ho  = tmp % 96; tmp /= 96;
    int o   = tmp % 64;
    int b   = tmp / 64;
    float s = 0.f, s2 = 0.f;
#pragma unroll
    for (int sl = 0; sl < 8; ++sl) {
        s  += partial[o * 8 + sl];
        s2 += partial[512 + o * 8 + sl];
    }
    float inv  = 1.f / (float)(NB * PLANE);
    float mean = s * inv;
    float var  = s2 * inv - mean * mean;
    float rsq  = rsqrtf(var + 1e-5f);
    float g  = gamma[o] * rsq;
    float bt = beta[o] - mean * g;
    const ushort* pl = outp + ((size_t)(b * COUT + o)) * PLANE + (2 * ho) * HW + 2 * wo;
    unsigned u01 = *(const unsigned*)pl;
    unsigned u23 = *(const unsigned*)(pl + HW);
    float y00 = fmaxf(g * bf2f((ushort)(u01 & 0xffff)) + bt, 0.f);
    float y01 = fmaxf(g * bf2f((ushort)(u01 >> 16))    + bt, 0.f);
    float y10 = fmaxf(g * bf2f((ushort)(u23 & 0xffff)) + bt, 0.f);
    float y11 = fmaxf(g * bf2f((ushort)(u23 >> 16))    + bt, 0.f);
    out[i] = fmaxf(fmaxf(y00, y01), fmaxf(y10, y11));
}

// ---------------- launcher --------------------------------------------------
extern "C" void kernel_launch(void* const* d_in, const int* in_sizes, int n_in,
                              void* d_out, int out_size, void* d_ws, size_t ws_size,
                              hipStream_t stream)
{
    const float* x      = (const float*)d_in[0];
    const float* w_p    = (const float*)d_in[1];
    const float* b_p    = (const float*)d_in[2];
    const float* w_m    = (const float*)d_in[3];
    const float* b_m    = (const float*)d_in[4];
    const float* w_conv = (const float*)d_in[5];
    const float* gamma  = (const float*)d_in[6];
    const float* beta   = (const float*)d_in[7];
    float* out = (float*)d_out;

    char* ws = (char*)d_ws;
    ushort* xt      = (ushort*)ws;                    // 4*194*200*64*2 = 19,865,600 B
    ushort* outp    = (ushort*)(ws + 19865600);       // 18,874,368 B
    float*  partial = (float*)(ws + 38739968);        // 4096 B
    ushort* wbf     = (ushort*)(ws + 38744064);       // 73,728 B
    ushort* womf    = (ushort*)(ws + 38817792);       // 36,864 B

    kpadprep<<<NB * H2 + 27, 256, 0, stream>>>(x, w_conv, w_p, w_m, xt, wbf, womf);
    kdeform<<<NPIX / 16, 256, 0, stream>>>(xt, wbf, womf, b_p, b_m, outp);
    kstats<<<512, 256, 0, stream>>>(outp, partial);
    kbnpool<<<(NB * COUT * 96 * 96) / 256, 256, 0, stream>>>(outp, partial, gamma, beta, out);
}